// Round 1
// baseline (399.903 us; speedup 1.0000x reference)
//
#include <hip/hip_runtime.h>
#include <stdint.h>

#ifndef FLT_MAX
#define FLT_MAX 3.402823466e+38f
#endif

static constexpr int NTOK = 16384;   // B*S
static constexpr int DD   = 512;
static constexpr int KK   = 1024;

static constexpr float DECAYF = 0.99f;
static constexpr float OMDEC  = 0.01f;
static constexpr float EPSF   = 1e-5f;

// ---------------- init: packed argmin keys + scalar accumulators ----------------
__global__ void k_init(unsigned long long* __restrict__ packed, float* __restrict__ scal) {
    int t = blockIdx.x * 256 + threadIdx.x;
    if (t < NTOK) packed[t] = ~0ULL;
    if (t == 0) { scal[0] = 0.f; scal[1] = 0.f; }
}

// ---------------- 0.5*||c||^2 per code ----------------
__global__ void k_cnorm(const float* __restrict__ cw, float* __restrict__ cnorm) {
    int k = blockIdx.x;
    int lane = threadIdx.x;           // 64 threads = 1 wave
    const float* row = cw + (size_t)k * DD;
    float s = 0.f;
#pragma unroll
    for (int i = 0; i < DD / 64; ++i) { float v = row[lane + i * 64]; s = fmaf(v, v, s); }
#pragma unroll
    for (int off = 32; off > 0; off >>= 1) s += __shfl_down(s, off, 64);
    if (lane == 0) cnorm[k] = 0.5f * s;
}

// ---------------- argmin over codes: tiled f32 "GEMM" + packed atomicMin ----------------
static constexpr int BM = 64;    // tokens per block
static constexpr int BN = 128;   // codes per tile
static constexpr int BK = 32;    // D chunk
static constexpr int YS = 4;     // codebook split across blockIdx.y

__global__ __launch_bounds__(256, 2) void k_argmin(
    const float* __restrict__ z, const float* __restrict__ cw,
    const float* __restrict__ cnorm, unsigned long long* __restrict__ packed)
{
    __shared__ float As[BK][BM + 4];   // [32][68]  z^T tile
    __shared__ float Bs[BK][BN + 4];   // [32][132] codes^T tile
    __shared__ unsigned long long red[BM];

    const int tid = threadIdx.x;
    const int tx = tid & 15;          // 16 -> 8 codes each = 128
    const int ty = tid >> 4;          // 16 -> 4 tokens each = 64
    const int t0 = blockIdx.x * BM;
    const int cbase = blockIdx.y * (KK / YS);

    float minv[4] = {FLT_MAX, FLT_MAX, FLT_MAX, FLT_MAX};
    int   mini[4] = {0, 0, 0, 0};

    for (int ct = 0; ct < (KK / YS) / BN; ++ct) {   // 2 code tiles per block
        const int c0 = cbase + ct * BN;
        float acc[4][8];
#pragma unroll
        for (int i = 0; i < 4; ++i)
#pragma unroll
            for (int j = 0; j < 8; ++j) acc[i][j] = 0.f;

        for (int dk = 0; dk < DD / BK; ++dk) {      // 16 D-chunks
            const int d0 = dk * BK;
            // stage z tile (64 tok x 32 d), transposed into As[d][tok]
#pragma unroll
            for (int i = 0; i < 2; ++i) {
                int lin = tid * 4 + i * 1024;
                int tok = lin >> 5, dd = lin & 31;
                float4 v = *reinterpret_cast<const float4*>(&z[(size_t)(t0 + tok) * DD + d0 + dd]);
                As[dd + 0][tok] = v.x; As[dd + 1][tok] = v.y;
                As[dd + 2][tok] = v.z; As[dd + 3][tok] = v.w;
            }
            // stage code tile (128 codes x 32 d), transposed into Bs[d][code]
#pragma unroll
            for (int i = 0; i < 4; ++i) {
                int lin = tid * 4 + i * 1024;
                int code = lin >> 5, dd = lin & 31;
                float4 v = *reinterpret_cast<const float4*>(&cw[(size_t)(c0 + code) * DD + d0 + dd]);
                Bs[dd + 0][code] = v.x; Bs[dd + 1][code] = v.y;
                Bs[dd + 2][code] = v.z; Bs[dd + 3][code] = v.w;
            }
            __syncthreads();
#pragma unroll
            for (int kk = 0; kk < BK; ++kk) {
                float4 av  = *reinterpret_cast<const float4*>(&As[kk][ty * 4]);
                float4 bv0 = *reinterpret_cast<const float4*>(&Bs[kk][tx * 8]);
                float4 bv1 = *reinterpret_cast<const float4*>(&Bs[kk][tx * 8 + 4]);
                float a[4] = {av.x, av.y, av.z, av.w};
                float b[8] = {bv0.x, bv0.y, bv0.z, bv0.w, bv1.x, bv1.y, bv1.z, bv1.w};
#pragma unroll
                for (int i = 0; i < 4; ++i)
#pragma unroll
                    for (int j = 0; j < 8; ++j)
                        acc[i][j] = fmaf(a[i], b[j], acc[i][j]);
            }
            __syncthreads();
        }
        // score = 0.5||c||^2 - z.c  (argmin-equivalent to full sq-euclidean)
#pragma unroll
        for (int j = 0; j < 8; ++j) {
            int code = c0 + tx * 8 + j;
            float cn = cnorm[code];
#pragma unroll
            for (int i = 0; i < 4; ++i) {
                float s = cn - acc[i][j];
                if (s < minv[i]) { minv[i] = s; mini[i] = code; }
            }
        }
    }

    if (tid < BM) red[tid] = ~0ULL;
    __syncthreads();
#pragma unroll
    for (int i = 0; i < 4; ++i) {
        unsigned int b = __float_as_uint(minv[i]);
        b = (b & 0x80000000u) ? ~b : (b | 0x80000000u);   // sortable float
        unsigned long long key = ((unsigned long long)b << 32) | (unsigned int)mini[i];
        atomicMin(&red[ty * 4 + i], key);
    }
    __syncthreads();
    if (tid < BM) atomicMin(&packed[t0 + tid], red[tid]);
}

// ---------------- gather quantized -> hidden, loss numerator, mask sum ----------------
__global__ void k_post(const float* __restrict__ z, const float* __restrict__ mask,
                       const float* __restrict__ cw, const unsigned long long* __restrict__ packed,
                       float* __restrict__ out_hidden, float* __restrict__ out_idx,
                       int* __restrict__ idx_ws, float* __restrict__ scal)
{
    const int tid = threadIdx.x;
    const int t0 = blockIdx.x * 64;
    __shared__ int sidx[64];
    if (tid < 64) {
        int t = t0 + tid;
        int idx = (int)(packed[t] & 0xFFFFFFFFu);
        sidx[tid] = idx;
        idx_ws[t] = idx;
        out_idx[t] = (float)idx;
    }
    __syncthreads();
    float lsum = 0.f, msum = 0.f;
    for (int i = 0; i < 64; ++i) {
        int t = t0 + i;
        int idx = sidx[i];
        float m = mask[t];
        const float* zr = z + (size_t)t * DD;
        const float* cr = cw + (size_t)idx * DD;
        float2 zv = *reinterpret_cast<const float2*>(&zr[tid * 2]);
        float2 cv = *reinterpret_cast<const float2*>(&cr[tid * 2]);
        *reinterpret_cast<float2*>(&out_hidden[(size_t)t * DD + tid * 2]) = cv;
        float dx = zv.x - cv.x, dy = zv.y - cv.y;
        lsum = fmaf(m, dx * dx + dy * dy, lsum);
        if (tid == 0) msum += m;
    }
    __shared__ float rs[256];
    rs[tid] = lsum;
    __syncthreads();
    for (int s = 128; s > 0; s >>= 1) { if (tid < s) rs[tid] += rs[tid + s]; __syncthreads(); }
    if (tid == 0) {
        atomicAdd(&scal[0], rs[0] * (1.0f / DD));
        atomicAdd(&scal[1], msum);
    }
}

// ---------------- per-code segment sums -> new_weight, n ----------------
__global__ void k_dw(const float* __restrict__ z, const float* __restrict__ mask,
                     const int* __restrict__ idx_ws, const float* __restrict__ ema_w,
                     float* __restrict__ out_nw, float* __restrict__ n_ws)
{
    const int k = blockIdx.x;
    const int tid = threadIdx.x;
    __shared__ int list[2048];
    __shared__ int cnt;
    float a0 = 0.f, a1 = 0.f, nk = 0.f;
    for (int base = 0; base < NTOK; base += 2048) {
        if (tid == 0) cnt = 0;
        __syncthreads();
        for (int j = tid; j < 2048; j += 256) {
            if (idx_ws[base + j] == k) {
                int p = atomicAdd(&cnt, 1);
                list[p] = base + j;
            }
        }
        __syncthreads();
        int c = cnt;
        for (int m = 0; m < c; ++m) {
            int t = list[m];
            float mv = mask[t];
            const float* zr = z + (size_t)t * DD;
            float2 zv = *reinterpret_cast<const float2*>(&zr[tid * 2]);
            a0 = fmaf(mv, zv.x, a0);
            a1 = fmaf(mv, zv.y, a1);
            nk += mv;
        }
        __syncthreads();
    }
    size_t o = (size_t)k * DD + tid * 2;
    out_nw[o]     = DECAYF * ema_w[o]     + OMDEC * a0;
    out_nw[o + 1] = DECAYF * ema_w[o + 1] + OMDEC * a1;
    if (tid == 0) n_ws[k] = nk;
}

// ---------------- new_count normalization + loss scalar ----------------
__global__ void k_final(const float* __restrict__ ema_count, const float* __restrict__ n_ws,
                        const float* __restrict__ scal, float* __restrict__ out_count,
                        float* __restrict__ out_loss)
{
    const int tid = threadIdx.x;
    __shared__ float rs[256];
    float s = 0.f;
    for (int i = tid; i < KK; i += 256) s += ema_count[i];
    rs[tid] = s;
    __syncthreads();
    for (int o = 128; o > 0; o >>= 1) { if (tid < o) rs[tid] += rs[tid + o]; __syncthreads(); }
    float total = DECAYF * rs[0] + OMDEC * scal[1];   // sum(new_count) pre-normalization
    float scale = total / (total + KK * EPSF);
    for (int i = tid; i < KK; i += 256) {
        float raw = DECAYF * ema_count[i] + OMDEC * n_ws[i];
        out_count[i] = (raw + EPSF) * scale;
    }
    if (tid == 0) out_loss[0] = 2.5f * scal[0] / scal[1];  // LOSS_SCALE*COMMIT_COEF = 2.5
}

extern "C" void kernel_launch(void* const* d_in, const int* in_sizes, int n_in,
                              void* d_out, int out_size, void* d_ws, size_t ws_size,
                              hipStream_t stream)
{
    const float* z         = (const float*)d_in[0];
    const float* mask      = (const float*)d_in[1];
    const float* cw        = (const float*)d_in[2];
    const float* ema_count = (const float*)d_in[3];
    const float* ema_w     = (const float*)d_in[4];

    float* out        = (float*)d_out;
    float* out_hidden = out;                               // [N, D]
    float* out_idx    = out + (size_t)NTOK * DD;           // [N]
    float* out_loss   = out_idx + NTOK;                    // [1]
    float* out_count  = out_loss + 1;                      // [K]
    float* out_nw     = out_count + KK;                    // [K, D]

    float* W = (float*)d_ws;
    float* cnorm = W;                                        // 1024 floats
    float* n_ws  = W + 1024;                                 // 1024 floats
    float* scal  = W + 2048;                                 // 2 floats (loss_num, mask_sum)
    unsigned long long* packed = (unsigned long long*)(W + 4096);  // N u64
    int* idx_ws = (int*)(W + 4096 + 2 * NTOK);               // N ints

    k_init  <<<dim3(NTOK / 256), dim3(256), 0, stream>>>(packed, scal);
    k_cnorm <<<dim3(KK),         dim3(64),  0, stream>>>(cw, cnorm);
    k_argmin<<<dim3(NTOK / BM, YS), dim3(256), 0, stream>>>(z, cw, cnorm, packed);
    k_post  <<<dim3(NTOK / 64), dim3(256), 0, stream>>>(z, mask, cw, packed,
                                                        out_hidden, out_idx, idx_ws, scal);
    k_dw    <<<dim3(KK),        dim3(256), 0, stream>>>(z, mask, idx_ws, ema_w, out_nw, n_ws);
    k_final <<<dim3(1),         dim3(256), 0, stream>>>(ema_count, n_ws, scal, out_count, out_loss);
}